// Round 5
// baseline (9162.204 us; speedup 1.0000x reference)
//
#include <hip/hip_runtime.h>
#include <hip/hip_bf16.h>
#include <math.h>

#define B_   64
#define T_   512
#define F_   256
#define ENC_ 256
#define P_   128
#define H_   256
#define K_   12
#define INV_TEMP 10.0f

typedef _Float16 half2v __attribute__((ext_vector_type(2)));
union U2H { unsigned int u; half2v h; };

// ---------------- helpers ----------------------------------------------------
__device__ __forceinline__ float dot2f16(unsigned int a, unsigned int b, float c) {
    U2H ua; ua.u = a; U2H ub; ub.u = b;
#if __has_builtin(__builtin_amdgcn_fdot2)
    return __builtin_amdgcn_fdot2(ua.h, ub.h, c, false);
#else
    return fmaf((float)ua.h.x, (float)ub.h.x, fmaf((float)ua.h.y, (float)ub.h.y, c));
#endif
}
__device__ __forceinline__ float wave_sum(float v) {
    #pragma unroll
    for (int o = 32; o > 0; o >>= 1) v += __shfl_down(v, o, 64);
    return v;
}

// ---------------- fold: Wc = W_enc @ W_proj, bc = b_enc @ W_proj + b_proj ----
__global__ void fold_kernel(const float* __restrict__ We, const float* __restrict__ be,
                            const float* __restrict__ Wp, const float* __restrict__ bp,
                            float* __restrict__ Wc, float* __restrict__ bc) {
    int f = blockIdx.x;      // 0..256 (256 == bias row)
    int p = threadIdx.x;     // 0..127
    if (f < F_) {
        float a = 0.f;
        for (int e = 0; e < ENC_; e++) a = fmaf(We[f * ENC_ + e], Wp[e * P_ + p], a);
        Wc[f * P_ + p] = a;
    } else {
        float a = bp[p];
        for (int e = 0; e < ENC_; e++) a = fmaf(be[e], Wp[e * P_ + p], a);
        bc[p] = a;
    }
}

// ---------------- Wh -> packed f16: Whh[i4*768+j] = rows 4i4..4i4+3 of col j -
__global__ void conv_whh(const float* __restrict__ Wh, uint2* __restrict__ Whh) {
    int idx = blockIdx.x * 256 + threadIdx.x;        // 49152 total
    int i4 = idx / 768, j = idx % 768;
    U2H lo, hi;
    lo.h.x = (_Float16)Wh[(size_t)(4 * i4 + 0) * 768 + j];
    lo.h.y = (_Float16)Wh[(size_t)(4 * i4 + 1) * 768 + j];
    hi.h.x = (_Float16)Wh[(size_t)(4 * i4 + 2) * 768 + j];
    hi.h.y = (_Float16)Wh[(size_t)(4 * i4 + 3) * 768 + j];
    Whh[idx] = make_uint2(lo.u, hi.u);
}

// ---------------- generic tiled f32 GEMM: C = A(MxK) @ B(KxN) + bias ---------
#define TS 64
#define KT 16
__global__ __launch_bounds__(256) void gemm_bias(const float* __restrict__ A,
                                                 const float* __restrict__ Bm,
                                                 const float* __restrict__ bias,
                                                 float* __restrict__ C,
                                                 int M, int N, int K) {
    __shared__ float As[KT][TS + 1];
    __shared__ float Bs[KT][TS];
    int tid = threadIdx.x;
    int bm = blockIdx.y * TS, bn = blockIdx.x * TS;
    int tx = tid & 15, ty = tid >> 4;
    float acc[4][4] = {};
    for (int k0 = 0; k0 < K; k0 += KT) {
        #pragma unroll
        for (int i = 0; i < 4; i++) {
            int idx = tid + i * 256;
            int m = idx >> 4, kk = idx & 15;
            int gm = bm + m;
            As[kk][m] = (gm < M) ? A[(size_t)gm * K + k0 + kk] : 0.f;
        }
        #pragma unroll
        for (int i = 0; i < 4; i++) {
            int idx = tid + i * 256;
            int kk = idx >> 6, n = idx & 63;
            Bs[kk][n] = Bm[(size_t)(k0 + kk) * N + bn + n];
        }
        __syncthreads();
        #pragma unroll
        for (int kk = 0; kk < KT; kk++) {
            float a0 = As[kk][ty * 4 + 0], a1 = As[kk][ty * 4 + 1];
            float a2 = As[kk][ty * 4 + 2], a3 = As[kk][ty * 4 + 3];
            float4 bq = *(const float4*)&Bs[kk][tx * 4];
            acc[0][0] = fmaf(a0, bq.x, acc[0][0]); acc[0][1] = fmaf(a0, bq.y, acc[0][1]);
            acc[0][2] = fmaf(a0, bq.z, acc[0][2]); acc[0][3] = fmaf(a0, bq.w, acc[0][3]);
            acc[1][0] = fmaf(a1, bq.x, acc[1][0]); acc[1][1] = fmaf(a1, bq.y, acc[1][1]);
            acc[1][2] = fmaf(a1, bq.z, acc[1][2]); acc[1][3] = fmaf(a1, bq.w, acc[1][3]);
            acc[2][0] = fmaf(a2, bq.x, acc[2][0]); acc[2][1] = fmaf(a2, bq.y, acc[2][1]);
            acc[2][2] = fmaf(a2, bq.z, acc[2][2]); acc[2][3] = fmaf(a2, bq.w, acc[2][3]);
            acc[3][0] = fmaf(a3, bq.x, acc[3][0]); acc[3][1] = fmaf(a3, bq.y, acc[3][1]);
            acc[3][2] = fmaf(a3, bq.z, acc[3][2]); acc[3][3] = fmaf(a3, bq.w, acc[3][3]);
        }
        __syncthreads();
    }
    #pragma unroll
    for (int i = 0; i < 4; i++) {
        int gm = bm + ty * 4 + i;
        if (gm >= M) continue;
        #pragma unroll
        for (int j = 0; j < 4; j++) {
            int gn = bn + tx * 4 + j;
            C[(size_t)gm * N + gn] = acc[i][j] + (bias ? bias[gn] : 0.f);
        }
    }
}

// ---------------- GRU scan: 256 threads/block, 1 block per batch -------------
// Thread j owns gate columns j (r), j+256 (z), j+512 (n). ONE barrier/step.
// Weight residency strategy (the r3/r4 spills, fixed):
//   - arch VGPR file is only v0..v255; the other 256 regs are AGPRs reachable
//     only via v_accvgpr_*. LLVM spilled to scratch instead of AGPRs.
//   - wR (128 dw) -> arch VGPRs. wZ,wN (256 dw) -> AGPRs via explicit inline
//     asm "a"-constraint writes; volatile reads in the loop stop LICM from
//     hoisting 256 values back into the arch file.
__global__ __attribute__((amdgpu_flat_work_group_size(256, 256), amdgpu_waves_per_eu(1, 1)))
void gru_kernel(const float* __restrict__ gi,
                const uint2* __restrict__ Whh,
                const float* __restrict__ bhn,
                float* __restrict__ c_seq) {
    int b = blockIdx.x;
    int j = threadIdx.x;                 // 0..255
    __shared__ uint2 hbuf[2][64];        // 2 x 256 f16 h values

    // wR in arch VGPRs
    uint2 wR[64];
    {
        const uint2* cR = Whh + j;
        #pragma unroll
        for (int i = 0; i < 64; i++) wR[i] = cR[(size_t)i * 768];
        #pragma unroll
        for (int i = 0; i < 64; i++) asm volatile("" : "+v"(wR[i].x), "+v"(wR[i].y));
    }
    // wZ, wN in AGPRs
    unsigned aZ[128], aN[128];
    {
        const uint2* cZ = Whh + 256 + j;
        const uint2* cN = Whh + 512 + j;
        #pragma unroll
        for (int i = 0; i < 64; i++) {
            uint2 z2 = cZ[(size_t)i * 768];
            uint2 n2 = cN[(size_t)i * 768];
            asm volatile("v_accvgpr_write_b32 %0, %1" : "=a"(aZ[2 * i])     : "v"(z2.x));
            asm volatile("v_accvgpr_write_b32 %0, %1" : "=a"(aZ[2 * i + 1]) : "v"(z2.y));
            asm volatile("v_accvgpr_write_b32 %0, %1" : "=a"(aN[2 * i])     : "v"(n2.x));
            asm volatile("v_accvgpr_write_b32 %0, %1" : "=a"(aN[2 * i + 1]) : "v"(n2.y));
        }
    }
    ((_Float16*)hbuf)[j] = (_Float16)0.f;    // hbuf[0] = 0
    float bh = bhn[j];
    float hloc = 0.f;
    __syncthreads();

    const float* gib = gi + (size_t)b * T_ * 768;
    float* cb = c_seq + (size_t)b * T_ * H_;
    int cur = 0;
    #pragma unroll 1
    for (int t = 0; t < T_; t++) {
        const float* gt = gib + (size_t)t * 768;
        float ir  = gt[j];
        float iz  = gt[256 + j];
        float inn = gt[512 + j];
        const uint2* h4 = hbuf[cur];
        float ar0 = 0.f, ar1 = 0.f, az0 = 0.f, az1 = 0.f, an0 = 0.f, an1 = 0.f;
        #pragma unroll
        for (int i = 0; i < 64; i++) {
            uint2 hv = h4[i];
            unsigned wz0, wz1, wn0, wn1;
            asm volatile("v_accvgpr_read_b32 %0, %1" : "=v"(wz0) : "a"(aZ[2 * i]));
            asm volatile("v_accvgpr_read_b32 %0, %1" : "=v"(wz1) : "a"(aZ[2 * i + 1]));
            asm volatile("v_accvgpr_read_b32 %0, %1" : "=v"(wn0) : "a"(aN[2 * i]));
            asm volatile("v_accvgpr_read_b32 %0, %1" : "=v"(wn1) : "a"(aN[2 * i + 1]));
            ar0 = dot2f16(hv.x, wR[i].x, ar0);
            ar1 = dot2f16(hv.y, wR[i].y, ar1);
            az0 = dot2f16(hv.x, wz0, az0);
            az1 = dot2f16(hv.y, wz1, az1);
            an0 = dot2f16(hv.x, wn0, an0);
            an1 = dot2f16(hv.y, wn1, an1);
        }
        float r  = 1.f / (1.f + expf(-(ir + ar0 + ar1)));
        float zg = 1.f / (1.f + expf(-(iz + az0 + az1)));
        float n  = tanhf(inn + r * (an0 + an1 + bh));
        hloc = (1.f - zg) * n + zg * hloc;
        cb[(size_t)t * H_ + j] = hloc;
        ((_Float16*)hbuf)[(cur ^ 1) * 256 + j] = (_Float16)hloc;
        __syncthreads();
        cur ^= 1;
    }
}

// ---------------- transpose z (BxTxP) -> zt (BxPxT) --------------------------
__global__ __launch_bounds__(256) void transpose_z(const float* __restrict__ z,
                                                   float* __restrict__ zt) {
    __shared__ float tile[32][33];
    int b = blockIdx.z;
    int t0 = blockIdx.x * 32, d0 = blockIdx.y * 32;
    int tx = threadIdx.x & 31, ty = threadIdx.x >> 5;   // 32 x 8
    #pragma unroll
    for (int i = 0; i < 32; i += 8)
        tile[ty + i][tx] = z[((size_t)b * T_ + t0 + ty + i) * P_ + d0 + tx];
    __syncthreads();
    #pragma unroll
    for (int i = 0; i < 32; i += 8)
        zt[((size_t)b * P_ + d0 + ty + i) * T_ + t0 + tx] = tile[tx][ty + i];
}

// ---------------- fused loss: pred tile GEMM + flash LSE, all k in one grid --
__global__ __launch_bounds__(256) void loss_fused(const float* __restrict__ c,
                                                  const float* __restrict__ Wp,
                                                  const float* __restrict__ bp,
                                                  const float* __restrict__ zt,
                                                  float* __restrict__ accum) {
    __shared__ float Pst[P_][TS + 1];    // pred^T: [k-dim 128][row 64]
    __shared__ float As[KT][TS + 1];
    __shared__ float Bs[KT][2 * TS];
    __shared__ float red[4];
    int k  = blockIdx.z + 1;
    int b  = blockIdx.y;
    int t0 = blockIdx.x * TS;
    int Tk = T_ - k;
    int tid = threadIdx.x;

    // ---- phase 1: pred tile (64 rows x 128 cols), microtile 4x8 -------------
    {
        int tx = tid & 15, ty = tid >> 4;
        float acc[4][8] = {};
        const float* cb  = c + ((size_t)b * T_ + t0) * H_;
        const float* wpk = Wp + (size_t)(k - 1) * H_ * P_;
        for (int k0 = 0; k0 < H_; k0 += KT) {
            #pragma unroll
            for (int i = 0; i < 4; i++) {
                int idx = tid + i * 256;
                int mm = idx >> 4, kk = idx & 15;
                As[kk][mm] = cb[(size_t)mm * H_ + k0 + kk];
            }
            #pragma unroll
            for (int i = 0; i < 8; i++) {
                int idx = tid + i * 256;
                int kk = idx >> 7, n = idx & 127;
                Bs[kk][n] = wpk[(size_t)(k0 + kk) * P_ + n];
            }
            __syncthreads();
            #pragma unroll
            for (int kk = 0; kk < KT; kk++) {
                float a0 = As[kk][ty * 4 + 0], a1 = As[kk][ty * 4 + 1];
                float a2 = As[kk][ty * 4 + 2], a3 = As[kk][ty * 4 + 3];
                float4 b0 = *(const float4*)&Bs[kk][tx * 8];
                float4 b1 = *(const float4*)&Bs[kk][tx * 8 + 4];
                acc[0][0] = fmaf(a0, b0.x, acc[0][0]); acc[0][1] = fmaf(a0, b0.y, acc[0][1]);
                acc[0][2] = fmaf(a0, b0.z, acc[0][2]); acc[0][3] = fmaf(a0, b0.w, acc[0][3]);
                acc[0][4] = fmaf(a0, b1.x, acc[0][4]); acc[0][5] = fmaf(a0, b1.y, acc[0][5]);
                acc[0][6] = fmaf(a0, b1.z, acc[0][6]); acc[0][7] = fmaf(a0, b1.w, acc[0][7]);
                acc[1][0] = fmaf(a1, b0.x, acc[1][0]); acc[1][1] = fmaf(a1, b0.y, acc[1][1]);
                acc[1][2] = fmaf(a1, b0.z, acc[1][2]); acc[1][3] = fmaf(a1, b0.w, acc[1][3]);
                acc[1][4] = fmaf(a1, b1.x, acc[1][4]); acc[1][5] = fmaf(a1, b1.y, acc[1][5]);
                acc[1][6] = fmaf(a1, b1.z, acc[1][6]); acc[1][7] = fmaf(a1, b1.w, acc[1][7]);
                acc[2][0] = fmaf(a2, b0.x, acc[2][0]); acc[2][1] = fmaf(a2, b0.y, acc[2][1]);
                acc[2][2] = fmaf(a2, b0.z, acc[2][2]); acc[2][3] = fmaf(a2, b0.w, acc[2][3]);
                acc[2][4] = fmaf(a2, b1.x, acc[2][4]); acc[2][5] = fmaf(a2, b1.y, acc[2][5]);
                acc[2][6] = fmaf(a2, b1.z, acc[2][6]); acc[2][7] = fmaf(a2, b1.w, acc[2][7]);
                acc[3][0] = fmaf(a3, b0.x, acc[3][0]); acc[3][1] = fmaf(a3, b0.y, acc[3][1]);
                acc[3][2] = fmaf(a3, b0.z, acc[3][2]); acc[3][3] = fmaf(a3, b0.w, acc[3][3]);
                acc[3][4] = fmaf(a3, b1.x, acc[3][4]); acc[3][5] = fmaf(a3, b1.y, acc[3][5]);
                acc[3][6] = fmaf(a3, b1.z, acc[3][6]); acc[3][7] = fmaf(a3, b1.w, acc[3][7]);
            }
            __syncthreads();
        }
        #pragma unroll
        for (int jj = 0; jj < 8; jj++) {
            float bias = bp[(size_t)(k - 1) * P_ + tx * 8 + jj];
            #pragma unroll
            for (int i = 0; i < 4; i++)
                Pst[tx * 8 + jj][ty * 4 + i] = acc[i][jj] + bias;
        }
    }
    __syncthreads();

    // ---- phase 2: flash over column tiles -----------------------------------
    int tx = tid & 15, ty = tid >> 4;
    float m[4], s[4], sl[4];
    #pragma unroll
    for (int i = 0; i < 4; i++) { m[i] = -INFINITY; s[i] = 0.f; sl[i] = 0.f; }
    const float* ztb = zt + (size_t)b * P_ * T_;

    for (int ct = 0; ct < Tk; ct += TS) {
        float acc[4][4] = {};
        for (int k0 = 0; k0 < P_; k0 += KT) {
            #pragma unroll
            for (int i = 0; i < 4; i++) {
                int idx = tid + i * 256;
                int kk = idx >> 6, n = idx & 63;
                int gc = ct + n;
                Bs[kk][n] = (gc < Tk) ? ztb[(size_t)(k0 + kk) * T_ + k + gc] : 0.f;
            }
            __syncthreads();
            #pragma unroll
            for (int kk = 0; kk < KT; kk++) {
                float a0 = Pst[k0 + kk][ty * 4 + 0], a1 = Pst[k0 + kk][ty * 4 + 1];
                float a2 = Pst[k0 + kk][ty * 4 + 2], a3 = Pst[k0 + kk][ty * 4 + 3];
                float4 bq = *(const float4*)&Bs[kk][tx * 4];
                acc[0][0] = fmaf(a0, bq.x, acc[0][0]); acc[0][1] = fmaf(a0, bq.y, acc[0][1]);
                acc[0][2] = fmaf(a0, bq.z, acc[0][2]); acc[0][3] = fmaf(a0, bq.w, acc[0][3]);
                acc[1][0] = fmaf(a1, bq.x, acc[1][0]); acc[1][1] = fmaf(a1, bq.y, acc[1][1]);
                acc[1][2] = fmaf(a1, bq.z, acc[1][2]); acc[1][3] = fmaf(a1, bq.w, acc[1][3]);
                acc[2][0] = fmaf(a2, bq.x, acc[2][0]); acc[2][1] = fmaf(a2, bq.y, acc[2][1]);
                acc[2][2] = fmaf(a2, bq.z, acc[2][2]); acc[2][3] = fmaf(a2, bq.w, acc[2][3]);
                acc[3][0] = fmaf(a3, bq.x, acc[3][0]); acc[3][1] = fmaf(a3, bq.y, acc[3][1]);
                acc[3][2] = fmaf(a3, bq.z, acc[3][2]); acc[3][3] = fmaf(a3, bq.w, acc[3][3]);
            }
            __syncthreads();
        }
        #pragma unroll
        for (int i = 0; i < 4; i++) {
            float l[4];
            float tmax = -INFINITY, tsum = 0.f;
            #pragma unroll
            for (int j = 0; j < 4; j++) {
                int gc = ct + tx * 4 + j;
                bool valid = gc < Tk;
                l[j] = valid ? acc[i][j] * INV_TEMP : -INFINITY;
                tmax = fmaxf(tmax, l[j]);
                tsum += valid ? l[j] : 0.f;
            }
            #pragma unroll
            for (int o = 1; o < 16; o <<= 1) {
                float ot = __shfl_xor(tmax, o, 64);
                tmax = fmaxf(tmax, ot);
            }
            float mnew = fmaxf(m[i], tmax);
            float e = 0.f;
            #pragma unroll
            for (int j = 0; j < 4; j++) e += expf(l[j] - mnew);
            #pragma unroll
            for (int o = 1; o < 16; o <<= 1) {
                e    += __shfl_xor(e, o, 64);
                tsum += __shfl_xor(tsum, o, 64);
            }
            s[i]  = s[i] * expf(m[i] - mnew) + e;
            m[i]  = mnew;
            sl[i] += tsum;
        }
    }
    float scale = 1.0f / ((float)K_ * (float)B_ * (float)Tk);
    float bs = 0.f;
    #pragma unroll
    for (int i = 0; i < 4; i++) {
        int gr = t0 + ty * 4 + i;
        if (gr < Tk) bs += m[i] + logf(s[i]) - sl[i] / (float)Tk;
    }
    if (tx != 0) bs = 0.f;
    bs = wave_sum(bs);
    if ((tid & 63) == 0) red[tid >> 6] = bs;
    __syncthreads();
    if (tid == 0)
        atomicAdd(&accum[(blockIdx.x * 809 + b * 67 + blockIdx.z * 131) & 1023],
                  (red[0] + red[1] + red[2] + red[3]) * scale);
}

__global__ void zero_accum(float* accum) { accum[threadIdx.x] = 0.f; }

__global__ void finalize(const float* __restrict__ accum, float* __restrict__ out) {
    int tid = threadIdx.x;
    __shared__ float red[4];
    float v = 0.f;
    for (int i = tid; i < 1024; i += 256) v += accum[i];
    float sres = wave_sum(v);
    if ((tid & 63) == 0) red[tid >> 6] = sres;
    __syncthreads();
    if (tid == 0) out[0] = red[0] + red[1] + red[2] + red[3];
}

// ---------------- launch -----------------------------------------------------
extern "C" void kernel_launch(void* const* d_in, const int* in_sizes, int n_in,
                              void* d_out, int out_size, void* d_ws, size_t ws_size,
                              hipStream_t stream) {
    const float* x      = (const float*)d_in[0];
    const float* W_enc  = (const float*)d_in[1];
    const float* b_enc  = (const float*)d_in[2];
    const float* W_proj = (const float*)d_in[3];
    const float* b_proj = (const float*)d_in[4];
    const float* Wi     = (const float*)d_in[5];
    const float* bi     = (const float*)d_in[6];
    const float* Wh     = (const float*)d_in[7];
    const float* bhn    = (const float*)d_in[8];
    const float* Wp     = (const float*)d_in[9];
    const float* bp     = (const float*)d_in[10];
    float* out = (float*)d_out;

    float* ws    = (float*)d_ws;
    float* Wc    = ws;                        // 32768
    float* bc    = Wc + 32768;                // 128
    float* accum = bc + 128;                  // 1024
    uint2* Whh   = (uint2*)(accum + 1024);    // 49152 uint2 = 98304 float-slots
    float* z     = accum + 1024 + 98304;      // B*T*P   = 4194304
    float* gi    = z + 4194304;               // B*T*3H  = 25165824
    float* c     = gi + 25165824;             // B*T*H   = 8388608
    float* zt    = gi;                        // aliases gi (dead after GRU): B*P*T

    const int MT = B_ * T_;                   // 32768

    zero_accum<<<1, 1024, 0, stream>>>(accum);
    fold_kernel<<<F_ + 1, P_, 0, stream>>>(W_enc, b_enc, W_proj, b_proj, Wc, bc);
    conv_whh<<<192, 256, 0, stream>>>(Wh, Whh);
    // z = x @ Wc + bc   (M=32768, N=128, K=256)
    gemm_bias<<<dim3(P_ / TS, MT / TS), 256, 0, stream>>>(x, Wc, bc, z, MT, P_, F_);
    // gi = z @ Wi + bi  (M=32768, N=768, K=128)
    gemm_bias<<<dim3(3 * H_ / TS, MT / TS), 256, 0, stream>>>(z, Wi, bi, gi, MT, 3 * H_, P_);
    // GRU scan: 256 threads, weights resident in VGPR+AGPR (explicit accvgpr)
    gru_kernel<<<B_, 256, 0, stream>>>(gi, Whh, bhn, c);
    // transpose z for coalesced column access in the fused loss
    transpose_z<<<dim3(T_ / 32, P_ / 32, B_), 256, 0, stream>>>(z, zt);
    // fused pred-GEMM + flash loss, all k in one dispatch
    loss_fused<<<dim3(8, B_, K_), 256, 0, stream>>>(c, Wp, bp, zt, accum);
    finalize<<<1, 256, 0, stream>>>(accum, out);
}

// Round 6
// 2579.726 us; speedup vs baseline: 3.5516x; 3.5516x over previous
//
#include <hip/hip_runtime.h>
#include <hip/hip_bf16.h>
#include <math.h>

#define B_   64
#define T_   512
#define F_   256
#define ENC_ 256
#define P_   128
#define H_   256
#define K_   12
#define INV_TEMP 10.0f

typedef _Float16 half2v __attribute__((ext_vector_type(2)));
union U2H { unsigned int u; half2v h; };

// ---------------- helpers ----------------------------------------------------
__device__ __forceinline__ float dot2f16(unsigned int a, unsigned int b, float c) {
    U2H ua; ua.u = a; U2H ub; ub.u = b;
#if __has_builtin(__builtin_amdgcn_fdot2)
    return __builtin_amdgcn_fdot2(ua.h, ub.h, c, false);
#else
    return fmaf((float)ua.h.x, (float)ub.h.x, fmaf((float)ua.h.y, (float)ub.h.y, c));
#endif
}
__device__ __forceinline__ float wave_sum(float v) {
    #pragma unroll
    for (int o = 32; o > 0; o >>= 1) v += __shfl_down(v, o, 64);
    return v;
}

// ---------------- fold: Wc = W_enc @ W_proj, bc = b_enc @ W_proj + b_proj ----
__global__ void fold_kernel(const float* __restrict__ We, const float* __restrict__ be,
                            const float* __restrict__ Wp, const float* __restrict__ bp,
                            float* __restrict__ Wc, float* __restrict__ bc) {
    int f = blockIdx.x;      // 0..256 (256 == bias row)
    int p = threadIdx.x;     // 0..127
    if (f < F_) {
        float a = 0.f;
        for (int e = 0; e < ENC_; e++) a = fmaf(We[f * ENC_ + e], Wp[e * P_ + p], a);
        Wc[f * P_ + p] = a;
    } else {
        float a = bp[p];
        for (int e = 0; e < ENC_; e++) a = fmaf(be[e], Wp[e * P_ + p], a);
        bc[p] = a;
    }
}

// ---------------- Wh -> packed f16: Whh[i4*768+j] = rows 4i4..4i4+3 of col j -
__global__ void conv_whh(const float* __restrict__ Wh, uint2* __restrict__ Whh) {
    int idx = blockIdx.x * 256 + threadIdx.x;        // 49152 total
    int i4 = idx / 768, j = idx % 768;
    U2H lo, hi;
    lo.h.x = (_Float16)Wh[(size_t)(4 * i4 + 0) * 768 + j];
    lo.h.y = (_Float16)Wh[(size_t)(4 * i4 + 1) * 768 + j];
    hi.h.x = (_Float16)Wh[(size_t)(4 * i4 + 2) * 768 + j];
    hi.h.y = (_Float16)Wh[(size_t)(4 * i4 + 3) * 768 + j];
    Whh[idx] = make_uint2(lo.u, hi.u);
}

// ---------------- generic tiled f32 GEMM: C = A(MxK) @ B(KxN) + bias ---------
#define TS 64
#define KT 16
__global__ __launch_bounds__(256) void gemm_bias(const float* __restrict__ A,
                                                 const float* __restrict__ Bm,
                                                 const float* __restrict__ bias,
                                                 float* __restrict__ C,
                                                 int M, int N, int K) {
    __shared__ float As[KT][TS + 4];   // +4 pad: staging store was 4-way conflicted at +1
    __shared__ float Bs[KT][TS];
    int tid = threadIdx.x;
    int bm = blockIdx.y * TS, bn = blockIdx.x * TS;
    int tx = tid & 15, ty = tid >> 4;
    float acc[4][4] = {};
    for (int k0 = 0; k0 < K; k0 += KT) {
        #pragma unroll
        for (int i = 0; i < 4; i++) {
            int idx = tid + i * 256;
            int m = idx >> 4, kk = idx & 15;
            int gm = bm + m;
            As[kk][m] = (gm < M) ? A[(size_t)gm * K + k0 + kk] : 0.f;
        }
        #pragma unroll
        for (int i = 0; i < 4; i++) {
            int idx = tid + i * 256;
            int kk = idx >> 6, n = idx & 63;
            Bs[kk][n] = Bm[(size_t)(k0 + kk) * N + bn + n];
        }
        __syncthreads();
        #pragma unroll
        for (int kk = 0; kk < KT; kk++) {
            float a0 = As[kk][ty * 4 + 0], a1 = As[kk][ty * 4 + 1];
            float a2 = As[kk][ty * 4 + 2], a3 = As[kk][ty * 4 + 3];
            float4 bq = *(const float4*)&Bs[kk][tx * 4];
            acc[0][0] = fmaf(a0, bq.x, acc[0][0]); acc[0][1] = fmaf(a0, bq.y, acc[0][1]);
            acc[0][2] = fmaf(a0, bq.z, acc[0][2]); acc[0][3] = fmaf(a0, bq.w, acc[0][3]);
            acc[1][0] = fmaf(a1, bq.x, acc[1][0]); acc[1][1] = fmaf(a1, bq.y, acc[1][1]);
            acc[1][2] = fmaf(a1, bq.z, acc[1][2]); acc[1][3] = fmaf(a1, bq.w, acc[1][3]);
            acc[2][0] = fmaf(a2, bq.x, acc[2][0]); acc[2][1] = fmaf(a2, bq.y, acc[2][1]);
            acc[2][2] = fmaf(a2, bq.z, acc[2][2]); acc[2][3] = fmaf(a2, bq.w, acc[2][3]);
            acc[3][0] = fmaf(a3, bq.x, acc[3][0]); acc[3][1] = fmaf(a3, bq.y, acc[3][1]);
            acc[3][2] = fmaf(a3, bq.z, acc[3][2]); acc[3][3] = fmaf(a3, bq.w, acc[3][3]);
        }
        __syncthreads();
    }
    #pragma unroll
    for (int i = 0; i < 4; i++) {
        int gm = bm + ty * 4 + i;
        if (gm >= M) continue;
        #pragma unroll
        for (int j = 0; j < 4; j++) {
            int gn = bn + tx * 4 + j;
            C[(size_t)gm * N + gn] = acc[i][j] + (bias ? bias[gn] : 0.f);
        }
    }
}

// ---------------- GRU scan: 512 threads/block, 1 block per batch -------------
// Thread (j = tid&255, half = tid>>8) owns gate columns j/j+256/j+512 for h
// rows [128*half, 128*half+128). Weights: 3 gates x 64 f16-pairs = 192 dw
// per thread -> fits UNDER the 256 arch-VGPR ceiling (the r3/r4/r5 spill was
// asking for 384 dw). waves_per_eu(2,2) caps occupancy at the 256-reg point.
// Partials meet in LDS; two barriers per step; gi prefetched one step ahead.
__global__ __attribute__((amdgpu_flat_work_group_size(512, 512), amdgpu_waves_per_eu(2, 2)))
void gru_kernel(const float* __restrict__ gi,
                const uint2* __restrict__ Whh,
                const float* __restrict__ bhn,
                float* __restrict__ c_seq) {
    int b    = blockIdx.x;
    int tid  = threadIdx.x;          // 0..511
    int j    = tid & 255;
    int half = tid >> 8;             // wave-uniform (waves 0-3: 0, waves 4-7: 1)
    __shared__ _Float16 hbuf[H_];    // current h as f16
    __shared__ float psr[2][256], psz[2][256], psn[2][256];

    // per-thread weights: rows 4*i4..4*i4+3 for i4 in [32*half, 32*half+32)
    uint2 wR[32], wZ[32], wN[32];
    {
        const uint2* base = Whh + (size_t)(half * 32) * 768;
        const uint2* cR = base + j;
        const uint2* cZ = base + 256 + j;
        const uint2* cN = base + 512 + j;
        #pragma unroll
        for (int i = 0; i < 32; i++) {
            wR[i] = cR[(size_t)i * 768];
            wZ[i] = cZ[(size_t)i * 768];
            wN[i] = cN[(size_t)i * 768];
        }
        #pragma unroll
        for (int i = 0; i < 32; i++) {
            asm volatile("" : "+v"(wR[i].x), "+v"(wR[i].y));
            asm volatile("" : "+v"(wZ[i].x), "+v"(wZ[i].y));
            asm volatile("" : "+v"(wN[i].x), "+v"(wN[i].y));
        }
    }
    if (tid < H_) hbuf[tid] = (_Float16)0.f;
    float bh = bhn[j];
    float hloc = 0.f;

    const float* gib = gi + (size_t)b * T_ * 768;
    float* cb = c_seq + (size_t)b * T_ * H_;
    // preload gi for t=0
    float ir = 0.f, iz = 0.f, inn = 0.f;
    if (tid < 256) { ir = gib[j]; iz = gib[256 + j]; inn = gib[512 + j]; }
    __syncthreads();

    const uint2* hw = (const uint2*)hbuf;    // 64 f16-pairs-of-pairs
    #pragma unroll 1
    for (int t = 0; t < T_; t++) {
        // prefetch next step's gi (latency hidden behind the dot loop)
        float nir = 0.f, niz = 0.f, ninn = 0.f;
        if (tid < 256) {
            int tn = (t + 1 < T_) ? t + 1 : t;
            const float* gtn = gib + (size_t)tn * 768;
            nir = gtn[j]; niz = gtn[256 + j]; ninn = gtn[512 + j];
        }
        // partial dots over this thread's 128 h rows
        float ar0 = 0.f, ar1 = 0.f, az0 = 0.f, az1 = 0.f, an0 = 0.f, an1 = 0.f;
        #pragma unroll
        for (int i = 0; i < 32; i++) {
            uint2 hv = hw[half * 32 + i];    // broadcast LDS read (wave-uniform)
            ar0 = dot2f16(hv.x, wR[i].x, ar0);
            ar1 = dot2f16(hv.y, wR[i].y, ar1);
            az0 = dot2f16(hv.x, wZ[i].x, az0);
            az1 = dot2f16(hv.y, wZ[i].y, az1);
            an0 = dot2f16(hv.x, wN[i].x, an0);
            an1 = dot2f16(hv.y, wN[i].y, an1);
        }
        psr[half][j] = ar0 + ar1;
        psz[half][j] = az0 + az1;
        psn[half][j] = an0 + an1;
        __syncthreads();
        if (tid < 256) {
            float ar = psr[0][j] + psr[1][j];
            float az = psz[0][j] + psz[1][j];
            float an = psn[0][j] + psn[1][j];
            float r  = 1.f / (1.f + expf(-(ir + ar)));
            float zg = 1.f / (1.f + expf(-(iz + az)));
            float n  = tanhf(inn + r * (an + bh));
            hloc = (1.f - zg) * n + zg * hloc;
            cb[(size_t)t * H_ + j] = hloc;
            hbuf[j] = (_Float16)hloc;
        }
        ir = nir; iz = niz; inn = ninn;
        __syncthreads();
    }
}

// ---------------- transpose z (BxTxP) -> zt (BxPxT) --------------------------
__global__ __launch_bounds__(256) void transpose_z(const float* __restrict__ z,
                                                   float* __restrict__ zt) {
    __shared__ float tile[32][33];
    int b = blockIdx.z;
    int t0 = blockIdx.x * 32, d0 = blockIdx.y * 32;
    int tx = threadIdx.x & 31, ty = threadIdx.x >> 5;   // 32 x 8
    #pragma unroll
    for (int i = 0; i < 32; i += 8)
        tile[ty + i][tx] = z[((size_t)b * T_ + t0 + ty + i) * P_ + d0 + tx];
    __syncthreads();
    #pragma unroll
    for (int i = 0; i < 32; i += 8)
        zt[((size_t)b * P_ + d0 + ty + i) * T_ + t0 + tx] = tile[tx][ty + i];
}

// ---------------- fused loss: pred tile GEMM + flash LSE, all k in one grid --
__global__ __launch_bounds__(256) void loss_fused(const float* __restrict__ c,
                                                  const float* __restrict__ Wp,
                                                  const float* __restrict__ bp,
                                                  const float* __restrict__ zt,
                                                  float* __restrict__ accum) {
    __shared__ float Pst[P_][TS + 1];    // pred^T: [k-dim 128][row 64]
    __shared__ float As[KT][TS + 4];
    __shared__ float Bs[KT][2 * TS];
    __shared__ float red[4];
    int k  = blockIdx.z + 1;
    int b  = blockIdx.y;
    int t0 = blockIdx.x * TS;
    int Tk = T_ - k;
    int tid = threadIdx.x;

    // ---- phase 1: pred tile (64 rows x 128 cols), microtile 4x8 -------------
    {
        int tx = tid & 15, ty = tid >> 4;
        float acc[4][8] = {};
        const float* cb  = c + ((size_t)b * T_ + t0) * H_;
        const float* wpk = Wp + (size_t)(k - 1) * H_ * P_;
        for (int k0 = 0; k0 < H_; k0 += KT) {
            #pragma unroll
            for (int i = 0; i < 4; i++) {
                int idx = tid + i * 256;
                int mm = idx >> 4, kk = idx & 15;
                As[kk][mm] = cb[(size_t)mm * H_ + k0 + kk];
            }
            #pragma unroll
            for (int i = 0; i < 8; i++) {
                int idx = tid + i * 256;
                int kk = idx >> 7, n = idx & 127;
                Bs[kk][n] = wpk[(size_t)(k0 + kk) * P_ + n];
            }
            __syncthreads();
            #pragma unroll
            for (int kk = 0; kk < KT; kk++) {
                float a0 = As[kk][ty * 4 + 0], a1 = As[kk][ty * 4 + 1];
                float a2 = As[kk][ty * 4 + 2], a3 = As[kk][ty * 4 + 3];
                float4 b0 = *(const float4*)&Bs[kk][tx * 8];
                float4 b1 = *(const float4*)&Bs[kk][tx * 8 + 4];
                acc[0][0] = fmaf(a0, b0.x, acc[0][0]); acc[0][1] = fmaf(a0, b0.y, acc[0][1]);
                acc[0][2] = fmaf(a0, b0.z, acc[0][2]); acc[0][3] = fmaf(a0, b0.w, acc[0][3]);
                acc[0][4] = fmaf(a0, b1.x, acc[0][4]); acc[0][5] = fmaf(a0, b1.y, acc[0][5]);
                acc[0][6] = fmaf(a0, b1.z, acc[0][6]); acc[0][7] = fmaf(a0, b1.w, acc[0][7]);
                acc[1][0] = fmaf(a1, b0.x, acc[1][0]); acc[1][1] = fmaf(a1, b0.y, acc[1][1]);
                acc[1][2] = fmaf(a1, b0.z, acc[1][2]); acc[1][3] = fmaf(a1, b0.w, acc[1][3]);
                acc[1][4] = fmaf(a1, b1.x, acc[1][4]); acc[1][5] = fmaf(a1, b1.y, acc[1][5]);
                acc[1][6] = fmaf(a1, b1.z, acc[1][6]); acc[1][7] = fmaf(a1, b1.w, acc[1][7]);
                acc[2][0] = fmaf(a2, b0.x, acc[2][0]); acc[2][1] = fmaf(a2, b0.y, acc[2][1]);
                acc[2][2] = fmaf(a2, b0.z, acc[2][2]); acc[2][3] = fmaf(a2, b0.w, acc[2][3]);
                acc[2][4] = fmaf(a2, b1.x, acc[2][4]); acc[2][5] = fmaf(a2, b1.y, acc[2][5]);
                acc[2][6] = fmaf(a2, b1.z, acc[2][6]); acc[2][7] = fmaf(a2, b1.w, acc[2][7]);
                acc[3][0] = fmaf(a3, b0.x, acc[3][0]); acc[3][1] = fmaf(a3, b0.y, acc[3][1]);
                acc[3][2] = fmaf(a3, b0.z, acc[3][2]); acc[3][3] = fmaf(a3, b0.w, acc[3][3]);
                acc[3][4] = fmaf(a3, b1.x, acc[3][4]); acc[3][5] = fmaf(a3, b1.y, acc[3][5]);
                acc[3][6] = fmaf(a3, b1.z, acc[3][6]); acc[3][7] = fmaf(a3, b1.w, acc[3][7]);
            }
            __syncthreads();
        }
        #pragma unroll
        for (int jj = 0; jj < 8; jj++) {
            float bias = bp[(size_t)(k - 1) * P_ + tx * 8 + jj];
            #pragma unroll
            for (int i = 0; i < 4; i++)
                Pst[tx * 8 + jj][ty * 4 + i] = acc[i][jj] + bias;
        }
    }
    __syncthreads();

    // ---- phase 2: flash over column tiles -----------------------------------
    int tx = tid & 15, ty = tid >> 4;
    float m[4], s[4], sl[4];
    #pragma unroll
    for (int i = 0; i < 4; i++) { m[i] = -INFINITY; s[i] = 0.f; sl[i] = 0.f; }
    const float* ztb = zt + (size_t)b * P_ * T_;

    for (int ct = 0; ct < Tk; ct += TS) {
        float acc[4][4] = {};
        for (int k0 = 0; k0 < P_; k0 += KT) {
            #pragma unroll
            for (int i = 0; i < 4; i++) {
                int idx = tid + i * 256;
                int kk = idx >> 6, n = idx & 63;
                int gc = ct + n;
                Bs[kk][n] = (gc < Tk) ? ztb[(size_t)(k0 + kk) * T_ + k + gc] : 0.f;
            }
            __syncthreads();
            #pragma unroll
            for (int kk = 0; kk < KT; kk++) {
                float a0 = Pst[k0 + kk][ty * 4 + 0], a1 = Pst[k0 + kk][ty * 4 + 1];
                float a2 = Pst[k0 + kk][ty * 4 + 2], a3 = Pst[k0 + kk][ty * 4 + 3];
                float4 bq = *(const float4*)&Bs[kk][tx * 4];
                acc[0][0] = fmaf(a0, bq.x, acc[0][0]); acc[0][1] = fmaf(a0, bq.y, acc[0][1]);
                acc[0][2] = fmaf(a0, bq.z, acc[0][2]); acc[0][3] = fmaf(a0, bq.w, acc[0][3]);
                acc[1][0] = fmaf(a1, bq.x, acc[1][0]); acc[1][1] = fmaf(a1, bq.y, acc[1][1]);
                acc[1][2] = fmaf(a1, bq.z, acc[1][2]); acc[1][3] = fmaf(a1, bq.w, acc[1][3]);
                acc[2][0] = fmaf(a2, bq.x, acc[2][0]); acc[2][1] = fmaf(a2, bq.y, acc[2][1]);
                acc[2][2] = fmaf(a2, bq.z, acc[2][2]); acc[2][3] = fmaf(a2, bq.w, acc[2][3]);
                acc[3][0] = fmaf(a3, bq.x, acc[3][0]); acc[3][1] = fmaf(a3, bq.y, acc[3][1]);
                acc[3][2] = fmaf(a3, bq.z, acc[3][2]); acc[3][3] = fmaf(a3, bq.w, acc[3][3]);
            }
            __syncthreads();
        }
        #pragma unroll
        for (int i = 0; i < 4; i++) {
            float l[4];
            float tmax = -INFINITY, tsum = 0.f;
            #pragma unroll
            for (int j = 0; j < 4; j++) {
                int gc = ct + tx * 4 + j;
                bool valid = gc < Tk;
                l[j] = valid ? acc[i][j] * INV_TEMP : -INFINITY;
                tmax = fmaxf(tmax, l[j]);
                tsum += valid ? l[j] : 0.f;
            }
            #pragma unroll
            for (int o = 1; o < 16; o <<= 1) {
                float ot = __shfl_xor(tmax, o, 64);
                tmax = fmaxf(tmax, ot);
            }
            float mnew = fmaxf(m[i], tmax);
            float e = 0.f;
            #pragma unroll
            for (int j = 0; j < 4; j++) e += expf(l[j] - mnew);
            #pragma unroll
            for (int o = 1; o < 16; o <<= 1) {
                e    += __shfl_xor(e, o, 64);
                tsum += __shfl_xor(tsum, o, 64);
            }
            s[i]  = s[i] * expf(m[i] - mnew) + e;
            m[i]  = mnew;
            sl[i] += tsum;
        }
    }
    float scale = 1.0f / ((float)K_ * (float)B_ * (float)Tk);
    float bs = 0.f;
    #pragma unroll
    for (int i = 0; i < 4; i++) {
        int gr = t0 + ty * 4 + i;
        if (gr < Tk) bs += m[i] + logf(s[i]) - sl[i] / (float)Tk;
    }
    if (tx != 0) bs = 0.f;
    bs = wave_sum(bs);
    if ((tid & 63) == 0) red[tid >> 6] = bs;
    __syncthreads();
    if (tid == 0)
        atomicAdd(&accum[(blockIdx.x * 809 + b * 67 + blockIdx.z * 131) & 1023],
                  (red[0] + red[1] + red[2] + red[3]) * scale);
}

__global__ void zero_accum(float* accum) { accum[threadIdx.x] = 0.f; }

__global__ void finalize(const float* __restrict__ accum, float* __restrict__ out) {
    int tid = threadIdx.x;
    __shared__ float red[4];
    float v = 0.f;
    for (int i = tid; i < 1024; i += 256) v += accum[i];
    float sres = wave_sum(v);
    if ((tid & 63) == 0) red[tid >> 6] = sres;
    __syncthreads();
    if (tid == 0) out[0] = red[0] + red[1] + red[2] + red[3];
}

// ---------------- launch -----------------------------------------------------
extern "C" void kernel_launch(void* const* d_in, const int* in_sizes, int n_in,
                              void* d_out, int out_size, void* d_ws, size_t ws_size,
                              hipStream_t stream) {
    const float* x      = (const float*)d_in[0];
    const float* W_enc  = (const float*)d_in[1];
    const float* b_enc  = (const float*)d_in[2];
    const float* W_proj = (const float*)d_in[3];
    const float* b_proj = (const float*)d_in[4];
    const float* Wi     = (const float*)d_in[5];
    const float* bi     = (const float*)d_in[6];
    const float* Wh     = (const float*)d_in[7];
    const float* bhn    = (const float*)d_in[8];
    const float* Wp     = (const float*)d_in[9];
    const float* bp     = (const float*)d_in[10];
    float* out = (float*)d_out;

    float* ws    = (float*)d_ws;
    float* Wc    = ws;                        // 32768
    float* bc    = Wc + 32768;                // 128
    float* accum = bc + 128;                  // 1024
    uint2* Whh   = (uint2*)(accum + 1024);    // 49152 uint2 = 98304 float-slots
    float* z     = accum + 1024 + 98304;      // B*T*P   = 4194304
    float* gi    = z + 4194304;               // B*T*3H  = 25165824
    float* c     = gi + 25165824;             // B*T*H   = 8388608
    float* zt    = gi;                        // aliases gi (dead after GRU): B*P*T

    const int MT = B_ * T_;                   // 32768

    zero_accum<<<1, 1024, 0, stream>>>(accum);
    fold_kernel<<<F_ + 1, P_, 0, stream>>>(W_enc, b_enc, W_proj, b_proj, Wc, bc);
    conv_whh<<<192, 256, 0, stream>>>(Wh, Whh);
    // z = x @ Wc + bc   (M=32768, N=128, K=256)
    gemm_bias<<<dim3(P_ / TS, MT / TS), 256, 0, stream>>>(x, Wc, bc, z, MT, P_, F_);
    // gi = z @ Wi + bi  (M=32768, N=768, K=128)
    gemm_bias<<<dim3(3 * H_ / TS, MT / TS), 256, 0, stream>>>(z, Wi, bi, gi, MT, 3 * H_, P_);
    // GRU scan: 512 threads, H-split, 192 dw/thread of f16 weights in VGPRs
    gru_kernel<<<B_, 512, 0, stream>>>(gi, Whh, bhn, c);
    // transpose z for coalesced column access in the fused loss
    transpose_z<<<dim3(T_ / 32, P_ / 32, B_), 256, 0, stream>>>(z, zt);
    // fused pred-GEMM + flash loss, all k in one dispatch
    loss_fused<<<dim3(8, B_, K_), 256, 0, stream>>>(c, Wp, bp, zt, accum);
    finalize<<<1, 256, 0, stream>>>(accum, out);
}

// Round 7
// 1509.434 us; speedup vs baseline: 6.0700x; 1.7091x over previous
//
#include <hip/hip_runtime.h>
#include <hip/hip_bf16.h>
#include <math.h>

#define B_   64
#define T_   512
#define F_   256
#define ENC_ 256
#define P_   128
#define H_   256
#define K_   12
#define INV_TEMP 10.0f

typedef unsigned short u16;
typedef _Float16 half2v __attribute__((ext_vector_type(2)));
union U2H { unsigned int u; half2v h; };
typedef __attribute__((ext_vector_type(8))) short bf16x8;   // 8 bf16 = 4 VGPRs
typedef __attribute__((ext_vector_type(4))) float f32x4;    // MFMA C/D

// ---------------- helpers ----------------------------------------------------
__device__ __forceinline__ float dot2f16(unsigned int a, unsigned int b, float c) {
    U2H ua; ua.u = a; U2H ub; ub.u = b;
#if __has_builtin(__builtin_amdgcn_fdot2)
    return __builtin_amdgcn_fdot2(ua.h, ub.h, c, false);
#else
    return fmaf((float)ua.h.x, (float)ub.h.x, fmaf((float)ua.h.y, (float)ub.h.y, c));
#endif
}
__device__ __forceinline__ u16 f2bf(float f) {   // RNE
    unsigned int u = __float_as_uint(f);
    unsigned int r = (u + 0x7fffu + ((u >> 16) & 1u)) >> 16;
    return (u16)r;
}
__device__ __forceinline__ float wave_sum(float v) {
    #pragma unroll
    for (int o = 32; o > 0; o >>= 1) v += __shfl_down(v, o, 64);
    return v;
}

// ---------------- fold: Wc = W_enc @ W_proj, bc = b_enc @ W_proj + b_proj ----
__global__ void fold_kernel(const float* __restrict__ We, const float* __restrict__ be,
                            const float* __restrict__ Wp, const float* __restrict__ bp,
                            float* __restrict__ Wc, float* __restrict__ bc) {
    int f = blockIdx.x;      // 0..256 (256 == bias row)
    int p = threadIdx.x;     // 0..127
    if (f < F_) {
        float a = 0.f;
        for (int e = 0; e < ENC_; e++) a = fmaf(We[f * ENC_ + e], Wp[e * P_ + p], a);
        Wc[f * P_ + p] = a;
    } else {
        float a = bp[p];
        for (int e = 0; e < ENC_; e++) a = fmaf(be[e], Wp[e * P_ + p], a);
        bc[p] = a;
    }
}

// ---------------- Wh -> packed f16: Whh[i4*768+j] = rows 4i4..4i4+3 of col j -
__global__ void conv_whh(const float* __restrict__ Wh, uint2* __restrict__ Whh) {
    int idx = blockIdx.x * 256 + threadIdx.x;        // 49152 total
    int i4 = idx / 768, j = idx % 768;
    U2H lo, hi;
    lo.h.x = (_Float16)Wh[(size_t)(4 * i4 + 0) * 768 + j];
    lo.h.y = (_Float16)Wh[(size_t)(4 * i4 + 1) * 768 + j];
    hi.h.x = (_Float16)Wh[(size_t)(4 * i4 + 2) * 768 + j];
    hi.h.y = (_Float16)Wh[(size_t)(4 * i4 + 3) * 768 + j];
    Whh[idx] = make_uint2(lo.u, hi.u);
}

// ---------------- fp32 -> bf16, 4 elems/thread -------------------------------
__global__ void conv_bf4(const float* __restrict__ src, u16* __restrict__ dst) {
    int i = blockIdx.x * 256 + threadIdx.x;
    float4 v = ((const float4*)src)[i];
    ushort4 o;
    o.x = f2bf(v.x); o.y = f2bf(v.y); o.z = f2bf(v.z); o.w = f2bf(v.w);
    ((ushort4*)dst)[i] = o;
}

// ---------------- Wp[k][h][p] fp32 -> Wpt[k][p][h] bf16 ----------------------
__global__ __launch_bounds__(256) void conv_wpt(const float* __restrict__ Wp,
                                                u16* __restrict__ Wpt) {
    __shared__ float tile[32][33];
    int kq = blockIdx.z;
    int h0 = blockIdx.x * 32, p0 = blockIdx.y * 32;
    int tx = threadIdx.x & 31, ty = threadIdx.x >> 5;
    #pragma unroll
    for (int i = 0; i < 32; i += 8)
        tile[ty + i][tx] = Wp[(size_t)kq * H_ * P_ + (size_t)(h0 + ty + i) * P_ + p0 + tx];
    __syncthreads();
    #pragma unroll
    for (int i = 0; i < 32; i += 8)
        Wpt[(size_t)kq * P_ * H_ + (size_t)(p0 + ty + i) * H_ + h0 + tx] = f2bf(tile[tx][ty + i]);
}

// ---------------- generic tiled f32 GEMM: C = A(MxK) @ B(KxN) + bias ---------
#define TS 64
#define KT 16
__global__ __launch_bounds__(256) void gemm_bias(const float* __restrict__ A,
                                                 const float* __restrict__ Bm,
                                                 const float* __restrict__ bias,
                                                 float* __restrict__ C,
                                                 int M, int N, int K) {
    __shared__ float As[KT][TS + 4];
    __shared__ float Bs[KT][TS];
    int tid = threadIdx.x;
    int bm = blockIdx.y * TS, bn = blockIdx.x * TS;
    int tx = tid & 15, ty = tid >> 4;
    float acc[4][4] = {};
    for (int k0 = 0; k0 < K; k0 += KT) {
        #pragma unroll
        for (int i = 0; i < 4; i++) {
            int idx = tid + i * 256;
            int m = idx >> 4, kk = idx & 15;
            int gm = bm + m;
            As[kk][m] = (gm < M) ? A[(size_t)gm * K + k0 + kk] : 0.f;
        }
        #pragma unroll
        for (int i = 0; i < 4; i++) {
            int idx = tid + i * 256;
            int kk = idx >> 6, n = idx & 63;
            Bs[kk][n] = Bm[(size_t)(k0 + kk) * N + bn + n];
        }
        __syncthreads();
        #pragma unroll
        for (int kk = 0; kk < KT; kk++) {
            float a0 = As[kk][ty * 4 + 0], a1 = As[kk][ty * 4 + 1];
            float a2 = As[kk][ty * 4 + 2], a3 = As[kk][ty * 4 + 3];
            float4 bq = *(const float4*)&Bs[kk][tx * 4];
            acc[0][0] = fmaf(a0, bq.x, acc[0][0]); acc[0][1] = fmaf(a0, bq.y, acc[0][1]);
            acc[0][2] = fmaf(a0, bq.z, acc[0][2]); acc[0][3] = fmaf(a0, bq.w, acc[0][3]);
            acc[1][0] = fmaf(a1, bq.x, acc[1][0]); acc[1][1] = fmaf(a1, bq.y, acc[1][1]);
            acc[1][2] = fmaf(a1, bq.z, acc[1][2]); acc[1][3] = fmaf(a1, bq.w, acc[1][3]);
            acc[2][0] = fmaf(a2, bq.x, acc[2][0]); acc[2][1] = fmaf(a2, bq.y, acc[2][1]);
            acc[2][2] = fmaf(a2, bq.z, acc[2][2]); acc[2][3] = fmaf(a2, bq.w, acc[2][3]);
            acc[3][0] = fmaf(a3, bq.x, acc[3][0]); acc[3][1] = fmaf(a3, bq.y, acc[3][1]);
            acc[3][2] = fmaf(a3, bq.z, acc[3][2]); acc[3][3] = fmaf(a3, bq.w, acc[3][3]);
        }
        __syncthreads();
    }
    #pragma unroll
    for (int i = 0; i < 4; i++) {
        int gm = bm + ty * 4 + i;
        if (gm >= M) continue;
        #pragma unroll
        for (int j = 0; j < 4; j++) {
            int gn = bn + tx * 4 + j;
            C[(size_t)gm * N + gn] = acc[i][j] + (bias ? bias[gn] : 0.f);
        }
    }
}

// ---------------- GRU scan (r6, unchanged — weights resident in VGPRs) -------
__global__ __attribute__((amdgpu_flat_work_group_size(512, 512), amdgpu_waves_per_eu(2, 2)))
void gru_kernel(const float* __restrict__ gi,
                const uint2* __restrict__ Whh,
                const float* __restrict__ bhn,
                float* __restrict__ c_seq) {
    int b    = blockIdx.x;
    int tid  = threadIdx.x;          // 0..511
    int j    = tid & 255;
    int half = tid >> 8;
    __shared__ _Float16 hbuf[H_];
    __shared__ float psr[2][256], psz[2][256], psn[2][256];

    uint2 wR[32], wZ[32], wN[32];
    {
        const uint2* base = Whh + (size_t)(half * 32) * 768;
        const uint2* cR = base + j;
        const uint2* cZ = base + 256 + j;
        const uint2* cN = base + 512 + j;
        #pragma unroll
        for (int i = 0; i < 32; i++) {
            wR[i] = cR[(size_t)i * 768];
            wZ[i] = cZ[(size_t)i * 768];
            wN[i] = cN[(size_t)i * 768];
        }
        #pragma unroll
        for (int i = 0; i < 32; i++) {
            asm volatile("" : "+v"(wR[i].x), "+v"(wR[i].y));
            asm volatile("" : "+v"(wZ[i].x), "+v"(wZ[i].y));
            asm volatile("" : "+v"(wN[i].x), "+v"(wN[i].y));
        }
    }
    if (tid < H_) hbuf[tid] = (_Float16)0.f;
    float bh = bhn[j];
    float hloc = 0.f;

    const float* gib = gi + (size_t)b * T_ * 768;
    float* cb = c_seq + (size_t)b * T_ * H_;
    float ir = 0.f, iz = 0.f, inn = 0.f;
    if (tid < 256) { ir = gib[j]; iz = gib[256 + j]; inn = gib[512 + j]; }
    __syncthreads();

    const uint2* hw = (const uint2*)hbuf;
    #pragma unroll 1
    for (int t = 0; t < T_; t++) {
        float nir = 0.f, niz = 0.f, ninn = 0.f;
        if (tid < 256) {
            int tn = (t + 1 < T_) ? t + 1 : t;
            const float* gtn = gib + (size_t)tn * 768;
            nir = gtn[j]; niz = gtn[256 + j]; ninn = gtn[512 + j];
        }
        float ar0 = 0.f, ar1 = 0.f, az0 = 0.f, az1 = 0.f, an0 = 0.f, an1 = 0.f;
        #pragma unroll
        for (int i = 0; i < 32; i++) {
            uint2 hv = hw[half * 32 + i];
            ar0 = dot2f16(hv.x, wR[i].x, ar0);
            ar1 = dot2f16(hv.y, wR[i].y, ar1);
            az0 = dot2f16(hv.x, wZ[i].x, az0);
            az1 = dot2f16(hv.y, wZ[i].y, az1);
            an0 = dot2f16(hv.x, wN[i].x, an0);
            an1 = dot2f16(hv.y, wN[i].y, an1);
        }
        psr[half][j] = ar0 + ar1;
        psz[half][j] = az0 + az1;
        psn[half][j] = an0 + an1;
        __syncthreads();
        if (tid < 256) {
            float ar = psr[0][j] + psr[1][j];
            float az = psz[0][j] + psz[1][j];
            float an = psn[0][j] + psn[1][j];
            float r  = 1.f / (1.f + expf(-(ir + ar)));
            float zg = 1.f / (1.f + expf(-(iz + az)));
            float n  = tanhf(inn + r * (an + bh));
            hloc = (1.f - zg) * n + zg * hloc;
            cb[(size_t)t * H_ + j] = hloc;
            hbuf[j] = (_Float16)hloc;
        }
        ir = nir; iz = niz; inn = ninn;
        __syncthreads();
    }
}

// ---------------- fused loss, MFMA edition -----------------------------------
// grid (8, B, K), 256 thr = 4 waves. Wave w owns rows [w*16, w*16+16).
// phase 1: Pst[64][128] = bf16( ch[b, t0:t0+64, :] @ Wp[k]^T-layout + bp[k] )
// phase 2: per 64-col tile: 16 MFMAs/wave; per-thread online softmax; one
//          cross-lane merge at the end (32 shuffles total vs 384 in fp32 ver).
// Layouts (m89/m120-verified): A[m=lane&15][k=quad*8+j], B[k=quad*8+j][n=lane&15],
// C/D col=lane&15, row=quad*4+reg.
__global__ __launch_bounds__(256) void loss_fused(const u16* __restrict__ ch,
                                                  const u16* __restrict__ Wpt,
                                                  const float* __restrict__ bp,
                                                  const u16* __restrict__ zh,
                                                  float* __restrict__ accum) {
    __shared__ u16 Pst[64][136];     // stride 136: pad kills the 8-way read conflict
    __shared__ float red[4];
    int k  = blockIdx.z + 1;
    int b  = blockIdx.y;
    int t0 = blockIdx.x * 64;
    int Tk = T_ - k;
    int tid  = threadIdx.x;
    int w    = tid >> 6;
    int lane = tid & 63;
    int col  = lane & 15;
    int quad = lane >> 4;

    // ---- phase 1 ------------------------------------------------------------
    {
        f32x4 acc[8] = {};
        const u16* arow = ch + ((size_t)b * T_ + t0 + w * 16 + col) * H_;
        const u16* wk   = Wpt + (size_t)(k - 1) * P_ * H_;
        #pragma unroll
        for (int k0 = 0; k0 < 8; k0++) {
            bf16x8 af = *(const bf16x8*)(arow + k0 * 32 + quad * 8);
            #pragma unroll
            for (int nt = 0; nt < 8; nt++) {
                bf16x8 bf = *(const bf16x8*)(wk + (size_t)(nt * 16 + col) * H_ + k0 * 32 + quad * 8);
                acc[nt] = __builtin_amdgcn_mfma_f32_16x16x32_bf16(af, bf, acc[nt], 0, 0, 0);
            }
        }
        #pragma unroll
        for (int nt = 0; nt < 8; nt++) {
            float bias = bp[(size_t)(k - 1) * P_ + nt * 16 + col];
            #pragma unroll
            for (int r = 0; r < 4; r++)
                Pst[w * 16 + quad * 4 + r][nt * 16 + col] = f2bf(acc[nt][r] + bias);
        }
    }
    __syncthreads();

    // ---- phase 2: flash LSE -------------------------------------------------
    float mloc[4], sloc[4], slsum[4];
    #pragma unroll
    for (int r = 0; r < 4; r++) { mloc[r] = -INFINITY; sloc[r] = 0.f; slsum[r] = 0.f; }
    const u16* zb = zh + (size_t)b * T_ * P_;

    for (int ct = 0; ct < Tk; ct += 64) {
        f32x4 acc[4] = {};
        #pragma unroll
        for (int k0 = 0; k0 < 4; k0++) {
            bf16x8 af = *(const bf16x8*)(&Pst[w * 16 + col][k0 * 32 + quad * 8]);
            #pragma unroll
            for (int nt = 0; nt < 4; nt++) {
                int tcol = k + ct + nt * 16 + col;   // may over-read <=16KB into slack (masked)
                bf16x8 bf = *(const bf16x8*)(zb + (size_t)tcol * P_ + k0 * 32 + quad * 8);
                acc[nt] = __builtin_amdgcn_mfma_f32_16x16x32_bf16(af, bf, acc[nt], 0, 0, 0);
            }
        }
        #pragma unroll
        for (int r = 0; r < 4; r++) {
            float l[4];
            float tmax = -INFINITY;
            #pragma unroll
            for (int nt = 0; nt < 4; nt++) {
                bool valid = (ct + nt * 16 + col) < Tk;
                l[nt] = valid ? acc[nt][r] * INV_TEMP : -INFINITY;
                tmax = fmaxf(tmax, l[nt]);
                slsum[r] += valid ? l[nt] : 0.f;
            }
            float mnew = fmaxf(mloc[r], tmax);   // finite except possibly tile 0 (all-valid there)
            float e = expf(l[0] - mnew) + expf(l[1] - mnew) + expf(l[2] - mnew) + expf(l[3] - mnew);
            sloc[r] = sloc[r] * expf(mloc[r] - mnew) + e;
            mloc[r] = mnew;
        }
    }
    // merge (m,s) and slsum across the 16 lanes of each quad-group
    #pragma unroll
    for (int r = 0; r < 4; r++) {
        #pragma unroll
        for (int o = 1; o < 16; o <<= 1) {
            float mo = __shfl_xor(mloc[r], o, 64);
            float so = __shfl_xor(sloc[r], o, 64);
            float mn = fmaxf(mloc[r], mo);
            sloc[r] = sloc[r] * expf(mloc[r] - mn) + so * expf(mo - mn);
            mloc[r] = mn;
            slsum[r] += __shfl_xor(slsum[r], o, 64);
        }
    }
    float scale = 1.0f / ((float)K_ * (float)B_ * (float)Tk);
    float bs = 0.f;
    #pragma unroll
    for (int r = 0; r < 4; r++) {
        int gr = t0 + w * 16 + quad * 4 + r;
        if (gr < Tk) bs += mloc[r] + logf(sloc[r]) - slsum[r] / (float)Tk;
    }
    if (col != 0) bs = 0.f;          // row value replicated across the 16 lanes
    bs = wave_sum(bs);
    if (lane == 0) red[w] = bs;
    __syncthreads();
    if (tid == 0)
        atomicAdd(&accum[(blockIdx.x * 809 + b * 67 + blockIdx.z * 131) & 1023],
                  (red[0] + red[1] + red[2] + red[3]) * scale);
}

__global__ void zero_accum(float* accum) { accum[threadIdx.x] = 0.f; }

__global__ void finalize(const float* __restrict__ accum, float* __restrict__ out) {
    int tid = threadIdx.x;
    __shared__ float red[4];
    float v = 0.f;
    for (int i = tid; i < 1024; i += 256) v += accum[i];
    float sres = wave_sum(v);
    if ((tid & 63) == 0) red[tid >> 6] = sres;
    __syncthreads();
    if (tid == 0) out[0] = red[0] + red[1] + red[2] + red[3];
}

// ---------------- launch -----------------------------------------------------
extern "C" void kernel_launch(void* const* d_in, const int* in_sizes, int n_in,
                              void* d_out, int out_size, void* d_ws, size_t ws_size,
                              hipStream_t stream) {
    const float* x      = (const float*)d_in[0];
    const float* W_enc  = (const float*)d_in[1];
    const float* b_enc  = (const float*)d_in[2];
    const float* W_proj = (const float*)d_in[3];
    const float* b_proj = (const float*)d_in[4];
    const float* Wi     = (const float*)d_in[5];
    const float* bi     = (const float*)d_in[6];
    const float* Wh     = (const float*)d_in[7];
    const float* bhn    = (const float*)d_in[8];
    const float* Wp     = (const float*)d_in[9];
    const float* bp     = (const float*)d_in[10];
    float* out = (float*)d_out;

    float* ws    = (float*)d_ws;
    float* Wc    = ws;                        // 32768
    float* bc    = Wc + 32768;                // 128
    float* accum = bc + 128;                  // 1024
    uint2* Whh   = (uint2*)(accum + 1024);    // 98304 float-slots
    float* z     = accum + 1024 + 98304;      // B*T*P   = 4194304
    float* gi    = z + 4194304;               // B*T*3H  = 25165824
    float* c     = gi + 25165824;             // B*T*H   = 8388608
    // bf16 buffers alias gi (dead after the GRU consumes it):
    u16* ch  = (u16*)gi;                                   // 8388608 u16 (4194304 fl)
    u16* zh  = (u16*)(gi + 4194304);                       // 4194304 u16 + 16KB slack
    u16* Wpt = (u16*)(gi + 4194304 + 2097152 + 4096);      // 393216 u16

    const int MT = B_ * T_;                   // 32768

    zero_accum<<<1, 1024, 0, stream>>>(accum);
    fold_kernel<<<F_ + 1, P_, 0, stream>>>(W_enc, b_enc, W_proj, b_proj, Wc, bc);
    conv_whh<<<192, 256, 0, stream>>>(Wh, Whh);
    // z = x @ Wc + bc   (M=32768, N=128, K=256)
    gemm_bias<<<dim3(P_ / TS, MT / TS), 256, 0, stream>>>(x, Wc, bc, z, MT, P_, F_);
    // gi = z @ Wi + bi  (M=32768, N=768, K=128)
    gemm_bias<<<dim3(3 * H_ / TS, MT / TS), 256, 0, stream>>>(z, Wi, bi, gi, MT, 3 * H_, P_);
    // GRU scan
    gru_kernel<<<B_, 512, 0, stream>>>(gi, Whh, bhn, c);
    // bf16 conversions (into the now-dead gi region)
    conv_bf4<<<8192, 256, 0, stream>>>(c, ch);     // c  -> ch
    conv_bf4<<<4096, 256, 0, stream>>>(z, zh);     // z  -> zh
    conv_wpt<<<dim3(8, 4, 12), 256, 0, stream>>>(Wp, Wpt);
    // fused pred-GEMM + flash loss (MFMA), all k in one dispatch
    loss_fused<<<dim3(8, B_, K_), 256, 0, stream>>>(ch, Wpt, bp, zh, accum);
    finalize<<<1, 256, 0, stream>>>(accum, out);
}

// Round 8
// 1366.948 us; speedup vs baseline: 6.7027x; 1.1042x over previous
//
#include <hip/hip_runtime.h>
#include <hip/hip_bf16.h>
#include <math.h>

#define B_   64
#define T_   512
#define F_   256
#define ENC_ 256
#define P_   128
#define H_   256
#define K_   12
#define INV_TEMP 10.0f

typedef unsigned short u16;
typedef _Float16 half2v __attribute__((ext_vector_type(2)));
union U2H { unsigned int u; half2v h; };
typedef __attribute__((ext_vector_type(8))) short bf16x8;   // 8 bf16 = 4 VGPRs
typedef __attribute__((ext_vector_type(4))) float f32x4;    // MFMA C/D

// ---------------- helpers ----------------------------------------------------
__device__ __forceinline__ float dot2f16(unsigned int a, unsigned int b, float c) {
    U2H ua; ua.u = a; U2H ub; ub.u = b;
#if __has_builtin(__builtin_amdgcn_fdot2)
    return __builtin_amdgcn_fdot2(ua.h, ub.h, c, false);
#else
    return fmaf((float)ua.h.x, (float)ub.h.x, fmaf((float)ua.h.y, (float)ub.h.y, c));
#endif
}
__device__ __forceinline__ float rcpf(float x) {
#if __has_builtin(__builtin_amdgcn_rcpf)
    return __builtin_amdgcn_rcpf(x);
#else
    return 1.f / x;
#endif
}
__device__ __forceinline__ u16 f2bf(float f) {   // RNE
    unsigned int u = __float_as_uint(f);
    unsigned int r = (u + 0x7fffu + ((u >> 16) & 1u)) >> 16;
    return (u16)r;
}
__device__ __forceinline__ float wave_sum(float v) {
    #pragma unroll
    for (int o = 32; o > 0; o >>= 1) v += __shfl_down(v, o, 64);
    return v;
}

// ---------------- fold: Wct[p][f] = bf16((W_enc@W_proj)[f][p]); bc -----------
__global__ void fold_kernel(const float* __restrict__ We, const float* __restrict__ be,
                            const float* __restrict__ Wp, const float* __restrict__ bp,
                            u16* __restrict__ Wct, float* __restrict__ bc) {
    int f = blockIdx.x;      // 0..256 (256 == bias row)
    int p = threadIdx.x;     // 0..127
    if (f < F_) {
        float a = 0.f;
        for (int e = 0; e < ENC_; e++) a = fmaf(We[f * ENC_ + e], Wp[e * P_ + p], a);
        Wct[(size_t)p * F_ + f] = f2bf(a);
    } else {
        float a = bp[p];
        for (int e = 0; e < ENC_; e++) a = fmaf(be[e], Wp[e * P_ + p], a);
        bc[p] = a;
    }
}

// ---------------- Wh -> packed f16: Whh[i4*768+j] = rows 4i4..4i4+3 of col j -
__global__ void conv_whh(const float* __restrict__ Wh, uint2* __restrict__ Whh) {
    int idx = blockIdx.x * 256 + threadIdx.x;        // 49152 total
    int i4 = idx / 768, j = idx % 768;
    U2H lo, hi;
    lo.h.x = (_Float16)Wh[(size_t)(4 * i4 + 0) * 768 + j];
    lo.h.y = (_Float16)Wh[(size_t)(4 * i4 + 1) * 768 + j];
    hi.h.x = (_Float16)Wh[(size_t)(4 * i4 + 2) * 768 + j];
    hi.h.y = (_Float16)Wh[(size_t)(4 * i4 + 3) * 768 + j];
    Whh[idx] = make_uint2(lo.u, hi.u);
}

// ---------------- fp32 -> bf16, 4 elems/thread -------------------------------
__global__ void conv_bf4(const float* __restrict__ src, u16* __restrict__ dst) {
    int i = blockIdx.x * 256 + threadIdx.x;
    float4 v = ((const float4*)src)[i];
    ushort4 o;
    o.x = f2bf(v.x); o.y = f2bf(v.y); o.z = f2bf(v.z); o.w = f2bf(v.w);
    ((ushort4*)dst)[i] = o;
}

// ---------------- Wi[k=128][n=768] fp32 -> Wit[n][k] bf16 --------------------
__global__ __launch_bounds__(256) void conv_wit(const float* __restrict__ Wi,
                                                u16* __restrict__ Wit) {
    __shared__ float tile[32][33];
    int n0 = blockIdx.x * 32, k0 = blockIdx.y * 32;
    int tx = threadIdx.x & 31, ty = threadIdx.x >> 5;
    #pragma unroll
    for (int i = 0; i < 32; i += 8)
        tile[ty + i][tx] = Wi[(size_t)(k0 + ty + i) * 768 + n0 + tx];
    __syncthreads();
    #pragma unroll
    for (int i = 0; i < 32; i += 8)
        Wit[(size_t)(n0 + ty + i) * 128 + k0 + tx] = f2bf(tile[tx][ty + i]);
}

// ---------------- Wp[k][h][p] fp32 -> Wpt[k][p][h] bf16 ----------------------
__global__ __launch_bounds__(256) void conv_wpt(const float* __restrict__ Wp,
                                                u16* __restrict__ Wpt) {
    __shared__ float tile[32][33];
    int kq = blockIdx.z;
    int h0 = blockIdx.x * 32, p0 = blockIdx.y * 32;
    int tx = threadIdx.x & 31, ty = threadIdx.x >> 5;
    #pragma unroll
    for (int i = 0; i < 32; i += 8)
        tile[ty + i][tx] = Wp[(size_t)kq * H_ * P_ + (size_t)(h0 + ty + i) * P_ + p0 + tx];
    __syncthreads();
    #pragma unroll
    for (int i = 0; i < 32; i += 8)
        Wpt[(size_t)kq * P_ * H_ + (size_t)(p0 + ty + i) * H_ + h0 + tx] = f2bf(tile[tx][ty + i]);
}

// ---------------- MFMA GEMM: C(MxN) = A(MxK,bf16) @ Bt(NxK,bf16)^T + bias ----
// Block: 64 rows x 128 cols, 4 waves (wave w: rows w*16..w*16+16).
// Verified fragment maps: A[m=lane&15][k=quad*8+j], B[k=quad*8+j][n=lane&15],
// C/D col=lane&15, row=quad*4+reg. Cf (fp32) and/or Ch (bf16) epilogues.
__global__ __launch_bounds__(256) void gemm_mfma(const u16* __restrict__ A,
                                                 const u16* __restrict__ Bt,
                                                 const float* __restrict__ bias,
                                                 float* __restrict__ Cf,
                                                 u16* __restrict__ Ch,
                                                 int N, int K) {
    int tid  = threadIdx.x;
    int w    = tid >> 6;
    int lane = tid & 63;
    int col  = lane & 15;
    int quad = lane >> 4;
    int bm = blockIdx.y * 64, bn = blockIdx.x * 128;

    f32x4 acc[8] = {};
    const u16* arow = A + (size_t)(bm + w * 16 + col) * K;
    #pragma unroll 4
    for (int k0 = 0; k0 < K; k0 += 32) {
        bf16x8 af = *(const bf16x8*)(arow + k0 + quad * 8);
        #pragma unroll
        for (int nt = 0; nt < 8; nt++) {
            bf16x8 bf = *(const bf16x8*)(Bt + (size_t)(bn + nt * 16 + col) * K + k0 + quad * 8);
            acc[nt] = __builtin_amdgcn_mfma_f32_16x16x32_bf16(af, bf, acc[nt], 0, 0, 0);
        }
    }
    #pragma unroll
    for (int nt = 0; nt < 8; nt++) {
        int gn = bn + nt * 16 + col;
        float bv = bias[gn];
        #pragma unroll
        for (int r = 0; r < 4; r++) {
            int gm = bm + w * 16 + quad * 4 + r;
            float v = acc[nt][r] + bv;
            if (Cf) Cf[(size_t)gm * N + gn] = v;
            if (Ch) Ch[(size_t)gm * N + gn] = f2bf(v);
        }
    }
}

// ---------------- GRU scan (r6 structure; fast gates; bf16 c output) ---------
__global__ __attribute__((amdgpu_flat_work_group_size(512, 512), amdgpu_waves_per_eu(2, 2)))
void gru_kernel(const float* __restrict__ gi,
                const uint2* __restrict__ Whh,
                const float* __restrict__ bhn,
                u16* __restrict__ ch) {
    int b    = blockIdx.x;
    int tid  = threadIdx.x;          // 0..511
    int j    = tid & 255;
    int half = tid >> 8;
    __shared__ _Float16 hbuf[H_];
    __shared__ float psr[2][256], psz[2][256], psn[2][256];

    uint2 wR[32], wZ[32], wN[32];
    {
        const uint2* base = Whh + (size_t)(half * 32) * 768;
        const uint2* cR = base + j;
        const uint2* cZ = base + 256 + j;
        const uint2* cN = base + 512 + j;
        #pragma unroll
        for (int i = 0; i < 32; i++) {
            wR[i] = cR[(size_t)i * 768];
            wZ[i] = cZ[(size_t)i * 768];
            wN[i] = cN[(size_t)i * 768];
        }
        #pragma unroll
        for (int i = 0; i < 32; i++) {
            asm volatile("" : "+v"(wR[i].x), "+v"(wR[i].y));
            asm volatile("" : "+v"(wZ[i].x), "+v"(wZ[i].y));
            asm volatile("" : "+v"(wN[i].x), "+v"(wN[i].y));
        }
    }
    if (tid < H_) hbuf[tid] = (_Float16)0.f;
    float bh = bhn[j];
    float hloc = 0.f;

    const float* gib = gi + (size_t)b * T_ * 768;
    u16* cb = ch + (size_t)b * T_ * H_;
    float ir = 0.f, iz = 0.f, inn = 0.f;
    if (tid < 256) { ir = gib[j]; iz = gib[256 + j]; inn = gib[512 + j]; }
    __syncthreads();

    const uint2* hw = (const uint2*)hbuf;
    #pragma unroll 1
    for (int t = 0; t < T_; t++) {
        float nir = 0.f, niz = 0.f, ninn = 0.f;
        if (tid < 256) {
            int tn = (t + 1 < T_) ? t + 1 : t;
            const float* gtn = gib + (size_t)tn * 768;
            nir = gtn[j]; niz = gtn[256 + j]; ninn = gtn[512 + j];
        }
        float ar0 = 0.f, ar1 = 0.f, az0 = 0.f, az1 = 0.f, an0 = 0.f, an1 = 0.f;
        #pragma unroll
        for (int i = 0; i < 32; i++) {
            uint2 hv = hw[half * 32 + i];
            ar0 = dot2f16(hv.x, wR[i].x, ar0);
            ar1 = dot2f16(hv.y, wR[i].y, ar1);
            az0 = dot2f16(hv.x, wZ[i].x, az0);
            az1 = dot2f16(hv.y, wZ[i].y, az1);
            an0 = dot2f16(hv.x, wN[i].x, an0);
            an1 = dot2f16(hv.y, wN[i].y, an1);
        }
        psr[half][j] = ar0 + ar1;
        psz[half][j] = az0 + az1;
        psn[half][j] = an0 + an1;
        __syncthreads();
        if (tid < 256) {
            float ar = psr[0][j] + psr[1][j];
            float az = psz[0][j] + psz[1][j];
            float an = psn[0][j] + psn[1][j];
            // sigmoid via fast exp + raw rcp; tanh(x) = 2/(1+e^{-2x}) - 1
            float r   = rcpf(1.f + __expf(-(ir + ar)));
            float zg  = rcpf(1.f + __expf(-(iz + az)));
            float xn  = inn + r * (an + bh);
            float n   = fmaf(2.f, rcpf(1.f + __expf(-2.f * xn)), -1.f);
            hloc = (1.f - zg) * n + zg * hloc;
            cb[(size_t)t * H_ + j] = f2bf(hloc);
            hbuf[j] = (_Float16)hloc;
        }
        ir = nir; iz = niz; inn = ninn;
        __syncthreads();
    }
}

// ---------------- fused loss, MFMA (r7 structure, fast exp/log) --------------
__global__ __launch_bounds__(256) void loss_fused(const u16* __restrict__ ch,
                                                  const u16* __restrict__ Wpt,
                                                  const float* __restrict__ bp,
                                                  const u16* __restrict__ zh,
                                                  float* __restrict__ accum) {
    __shared__ u16 Pst[64][136];
    __shared__ float red[4];
    int k  = blockIdx.z + 1;
    int b  = blockIdx.y;
    int t0 = blockIdx.x * 64;
    int Tk = T_ - k;
    int tid  = threadIdx.x;
    int w    = tid >> 6;
    int lane = tid & 63;
    int col  = lane & 15;
    int quad = lane >> 4;

    // ---- phase 1: Pst = bf16(ch-tile @ Wp[k] + bp[k]) -----------------------
    {
        f32x4 acc[8] = {};
        const u16* arow = ch + ((size_t)b * T_ + t0 + w * 16 + col) * H_;
        const u16* wk   = Wpt + (size_t)(k - 1) * P_ * H_;
        #pragma unroll
        for (int k0 = 0; k0 < 8; k0++) {
            bf16x8 af = *(const bf16x8*)(arow + k0 * 32 + quad * 8);
            #pragma unroll
            for (int nt = 0; nt < 8; nt++) {
                bf16x8 bf = *(const bf16x8*)(wk + (size_t)(nt * 16 + col) * H_ + k0 * 32 + quad * 8);
                acc[nt] = __builtin_amdgcn_mfma_f32_16x16x32_bf16(af, bf, acc[nt], 0, 0, 0);
            }
        }
        #pragma unroll
        for (int nt = 0; nt < 8; nt++) {
            float bias = bp[(size_t)(k - 1) * P_ + nt * 16 + col];
            #pragma unroll
            for (int r = 0; r < 4; r++)
                Pst[w * 16 + quad * 4 + r][nt * 16 + col] = f2bf(acc[nt][r] + bias);
        }
    }
    __syncthreads();

    // ---- phase 2: flash LSE -------------------------------------------------
    float mloc[4], sloc[4], slsum[4];
    #pragma unroll
    for (int r = 0; r < 4; r++) { mloc[r] = -INFINITY; sloc[r] = 0.f; slsum[r] = 0.f; }
    const u16* zb = zh + (size_t)b * T_ * P_;

    for (int ct = 0; ct < Tk; ct += 64) {
        f32x4 acc[4] = {};
        #pragma unroll
        for (int k0 = 0; k0 < 4; k0++) {
            bf16x8 af = *(const bf16x8*)(&Pst[w * 16 + col][k0 * 32 + quad * 8]);
            #pragma unroll
            for (int nt = 0; nt < 4; nt++) {
                int tcol = k + ct + nt * 16 + col;   // may over-read into slack (masked)
                bf16x8 bf = *(const bf16x8*)(zb + (size_t)tcol * P_ + k0 * 32 + quad * 8);
                acc[nt] = __builtin_amdgcn_mfma_f32_16x16x32_bf16(af, bf, acc[nt], 0, 0, 0);
            }
        }
        #pragma unroll
        for (int r = 0; r < 4; r++) {
            float l[4];
            float tmax = -INFINITY;
            #pragma unroll
            for (int nt = 0; nt < 4; nt++) {
                bool valid = (ct + nt * 16 + col) < Tk;
                l[nt] = valid ? acc[nt][r] * INV_TEMP : -INFINITY;
                tmax = fmaxf(tmax, l[nt]);
                slsum[r] += valid ? l[nt] : 0.f;
            }
            float mnew = fmaxf(mloc[r], tmax);
            float e = __expf(l[0] - mnew) + __expf(l[1] - mnew)
                    + __expf(l[2] - mnew) + __expf(l[3] - mnew);
            sloc[r] = sloc[r] * __expf(mloc[r] - mnew) + e;
            mloc[r] = mnew;
        }
    }
    #pragma unroll
    for (int r = 0; r < 4; r++) {
        #pragma unroll
        for (int o = 1; o < 16; o <<= 1) {
            float mo = __shfl_xor(mloc[r], o, 64);
            float so = __shfl_xor(sloc[r], o, 64);
            float mn = fmaxf(mloc[r], mo);
            sloc[r] = sloc[r] * __expf(mloc[r] - mn) + so * __expf(mo - mn);
            mloc[r] = mn;
            slsum[r] += __shfl_xor(slsum[r], o, 64);
        }
    }
    float scale = 1.0f / ((float)K_ * (float)B_ * (float)Tk);
    float bs = 0.f;
    #pragma unroll
    for (int r = 0; r < 4; r++) {
        int gr = t0 + w * 16 + quad * 4 + r;
        if (gr < Tk) bs += mloc[r] + __logf(sloc[r]) - slsum[r] / (float)Tk;
    }
    if (col != 0) bs = 0.f;
    bs = wave_sum(bs);
    if (lane == 0) red[w] = bs;
    __syncthreads();
    if (tid == 0)
        atomicAdd(&accum[(blockIdx.x * 809 + b * 67 + blockIdx.z * 131) & 1023],
                  (red[0] + red[1] + red[2] + red[3]) * scale);
}

__global__ void zero_accum(float* accum) { accum[threadIdx.x] = 0.f; }

__global__ void finalize(const float* __restrict__ accum, float* __restrict__ out) {
    int tid = threadIdx.x;
    __shared__ float red[4];
    float v = 0.f;
    for (int i = tid; i < 1024; i += 256) v += accum[i];
    float sres = wave_sum(v);
    if ((tid & 63) == 0) red[tid >> 6] = sres;
    __syncthreads();
    if (tid == 0) out[0] = red[0] + red[1] + red[2] + red[3];
}

// ---------------- launch -----------------------------------------------------
extern "C" void kernel_launch(void* const* d_in, const int* in_sizes, int n_in,
                              void* d_out, int out_size, void* d_ws, size_t ws_size,
                              hipStream_t stream) {
    const float* x      = (const float*)d_in[0];
    const float* W_enc  = (const float*)d_in[1];
    const float* b_enc  = (const float*)d_in[2];
    const float* W_proj = (const float*)d_in[3];
    const float* b_proj = (const float*)d_in[4];
    const float* Wi     = (const float*)d_in[5];
    const float* bi     = (const float*)d_in[6];
    const float* Wh     = (const float*)d_in[7];
    const float* bhn    = (const float*)d_in[8];
    const float* Wp     = (const float*)d_in[9];
    const float* bp     = (const float*)d_in[10];
    float* out = (float*)d_out;

    // layout (float offsets)
    float* ws    = (float*)d_ws;
    float* bc    = ws;                         // 128
    float* accum = bc + 128;                   // 1024
    uint2* Whh   = (uint2*)(accum + 1024);     // 49152 uint2 = 98304 fl -> end 99456
    u16* Wct     = (u16*)(ws + 99456);         // 32768 u16 = 16384 fl  -> end 115840
    u16* Wit     = (u16*)(ws + 115840);        // 98304 u16 = 49152 fl  -> end 164992
    u16* Wpt     = (u16*)(ws + 164992);        // 393216 u16 = 196608 fl-> end 361600
    u16* zh      = (u16*)(ws + 361600);        // 4194304 u16 = 2097152 fl (+4096 fl slack) -> end 2462848
    float* gi    = ws + 2462848;               // 25165824 fl -> end 27628672
    u16* xh      = (u16*)gi;                   // aliases gi[0:4194304 fl] (dead before gemm2 finishes... consumed by gemm1)
    u16* ch      = (u16*)(ws + 27628672);      // 8388608 u16 = 4194304 fl -> end 31822976 (~127 MB)

    const int MT = B_ * T_;                    // 32768

    zero_accum<<<1, 1024, 0, stream>>>(accum);
    fold_kernel<<<F_ + 1, P_, 0, stream>>>(W_enc, b_enc, W_proj, b_proj, Wct, bc);
    conv_whh<<<192, 256, 0, stream>>>(Wh, Whh);
    conv_wit<<<dim3(24, 4), 256, 0, stream>>>(Wi, Wit);
    conv_wpt<<<dim3(8, 4, 12), 256, 0, stream>>>(Wp, Wpt);
    conv_bf4<<<8192, 256, 0, stream>>>(x, xh);                  // x -> bf16
    // zh = bf16(xh @ Wct^T + bc)   (M=32768, N=128, K=256)
    gemm_mfma<<<dim3(1, MT / 64), 256, 0, stream>>>(xh, Wct, bc, nullptr, zh, P_, F_);
    // gi = zh @ Wit^T + bi         (M=32768, N=768, K=128)
    gemm_mfma<<<dim3(6, MT / 64), 256, 0, stream>>>(zh, Wit, bi, gi, nullptr, 3 * H_, P_);
    // GRU scan -> ch (bf16)
    gru_kernel<<<B_, 512, 0, stream>>>(gi, Whh, bhn, ch);
    // fused pred-GEMM + flash loss (MFMA), all k in one dispatch
    loss_fused<<<dim3(8, B_, K_), 256, 0, stream>>>(ch, Wpt, bp, zh, accum);
    finalize<<<1, 256, 0, stream>>>(accum, out);
}